// Round 6
// baseline (495.208 us; speedup 1.0000x reference)
//
#include <hip/hip_runtime.h>
#include <math.h>

#define N_NODES 20000
#define N_EDGES 640000

typedef __attribute__((ext_vector_type(8))) short short8;
typedef __attribute__((ext_vector_type(4))) float floatx4;

__device__ __forceinline__ float elu_f(float v) { return v > 0.f ? v : expm1f(v); }

__device__ __forceinline__ unsigned short bf16_rne(float f) {
  union { float f; unsigned u; } v;
  v.f = f;
  unsigned r = v.u + 0x7FFF + ((v.u >> 16) & 1);
  return (unsigned short)(r >> 16);
}

__device__ __forceinline__ float bf_to_f(unsigned short u) {
  union { unsigned u; float f; } v;
  v.u = (unsigned)u << 16;
  return v.f;
}

// bank-swizzled position within a channel block (keeps 8-aligned groups, spreads banks)
__device__ __forceinline__ int swz(int c) {
  return (c & ~7) | ((((c & 7) + ((c >> 3) >> 2))) & 7);
}

// ---------------- CSR build ----------------

__global__ void zero_int_kernel(int* p, int n) {
  int i = blockIdx.x * 256 + threadIdx.x;
  if (i < n) p[i] = 0;
}

__global__ void hist_kernel(const int* __restrict__ dst, int* __restrict__ cnt, int ne) {
  int e = blockIdx.x * 256 + threadIdx.x;
  if (e < ne) atomicAdd(&cnt[dst[e]], 1);
}

__global__ __launch_bounds__(1024) void scan_kernel(const int* __restrict__ cnt,
                                                    int* __restrict__ row_ptr,
                                                    int* __restrict__ row_next, int n) {
  __shared__ int part[1024];
  int t = threadIdx.x;
  int per = (n + 1023) / 1024;
  int base = t * per;
  int local = 0;
  for (int i = 0; i < per; ++i) {
    int idx = base + i;
    if (idx < n) local += cnt[idx];
  }
  part[t] = local;
  __syncthreads();
  for (int off = 1; off < 1024; off <<= 1) {
    int v = (t >= off) ? part[t - off] : 0;
    __syncthreads();
    part[t] += v;
    __syncthreads();
  }
  int prefix = (t == 0) ? 0 : part[t - 1];
  for (int i = 0; i < per; ++i) {
    int idx = base + i;
    if (idx < n) {
      row_ptr[idx] = prefix;
      row_next[idx] = prefix;
      prefix += cnt[idx];
    }
  }
  if (t == 1023) row_ptr[n] = part[1023];
}

__global__ void fill_kernel(const int* __restrict__ dst, int* __restrict__ row_next,
                            int* __restrict__ csr_eid, int ne) {
  int e = blockIdx.x * 256 + threadIdx.x;
  if (e >= ne) return;
  int pos = atomicAdd(&row_next[dst[e]], 1);
  csr_eid[pos] = e;
}

// ---------------- weight cast+transpose: Bt[n][k] = bf16(W[k][n]) ----------------

__global__ void wt_all_kernel(const float* __restrict__ W1, const float* __restrict__ W2,
                              const float* __restrict__ W3, unsigned short* __restrict__ Bt1,
                              unsigned short* __restrict__ Bt2, unsigned short* __restrict__ Bt3) {
  int idx = blockIdx.x * 256 + threadIdx.x;
  const float* W; unsigned short* Bt; int K, Nc, local;
  if (idx < 16384)      { W = W1; Bt = Bt1; K = 64;  Nc = 256; local = idx; }
  else if (idx < 81920) { W = W2; Bt = Bt2; K = 256; Nc = 256; local = idx - 16384; }
  else if (idx < 98304) { W = W3; Bt = Bt3; K = 256; Nc = 64;  local = idx - 81920; }
  else return;
  int k = local / Nc, n = local - k * Nc;
  Bt[(size_t)n * K + k] = bf16_rne(W[local]);
}

// ---------------- prep: u_s/u_d (layer1 alpha proj to input space) + aeproj all ----
// u_s[h*64+k] = sum_c W1[k, h*64+c]*as1[h,c];  proj[0..11] L1, [12..23] L2, [24..26] L3

__global__ void prep_kernel(const float* __restrict__ W1, const float* __restrict__ as1,
                            const float* __restrict__ ad1, const float* __restrict__ We1,
                            const float* __restrict__ ae1, const float* __restrict__ We2,
                            const float* __restrict__ ae2, const float* __restrict__ We3,
                            const float* __restrict__ ae3, float* __restrict__ u_s,
                            float* __restrict__ u_d, float* __restrict__ proj) {
  int t = threadIdx.x;
  if (t < 256) {
    int h = t >> 6, k = t & 63;
    float ss = 0.f, sd = 0.f;
    for (int c = 0; c < 64; ++c) {
      float w = W1[k * 256 + h * 64 + c];
      ss += w * as1[h * 64 + c];
      sd += w * ad1[h * 64 + c];
    }
    u_s[t] = ss;
    u_d[t] = sd;
  } else if (t < 256 + 12) {
    int u = t - 256; int d = u >> 2, h = u & 3;
    float s = 0.f;
    for (int c = 0; c < 64; ++c) s += We1[d * 256 + h * 64 + c] * ae1[h * 64 + c];
    proj[u] = s;
  } else if (t < 256 + 24) {
    int u = t - 256 - 12; int d = u >> 2, h = u & 3;
    float s = 0.f;
    for (int c = 0; c < 64; ++c) s += We2[d * 256 + h * 64 + c] * ae2[h * 64 + c];
    proj[12 + u] = s;
  } else if (t < 256 + 27) {
    int d = t - 256 - 24;
    float s = 0.f;
    for (int c = 0; c < 64; ++c) s += We3[d * 64 + c] * ae3[c];
    proj[24 + d] = s;
  }
}

// ---------------- input projection + layer-1 alpha dots (wave per node) -------------

__global__ void in_proj_alpha_kernel(const float* __restrict__ x, const float* __restrict__ Wp,
                                     const float* __restrict__ bp, const float* __restrict__ u_s,
                                     const float* __restrict__ u_d,
                                     unsigned short* __restrict__ h_bf,
                                     float* __restrict__ alp_s, float* __restrict__ alp_d,
                                     int n) {
  int gid = blockIdx.x * 256 + threadIdx.x;
  int w = gid >> 6, lane = gid & 63;
  if (w >= n) return;
  float v = elu_f(x[w * 2] * Wp[lane] + x[w * 2 + 1] * Wp[64 + lane] + bp[lane]);
  h_bf[w * 64 + lane] = bf16_rne(v);
  #pragma unroll
  for (int h = 0; h < 4; ++h) {
    float ps = v * u_s[h * 64 + lane];
    float pd = v * u_d[h * 64 + lane];
    #pragma unroll
    for (int off = 32; off; off >>= 1) {
      ps += __shfl_down(ps, off);
      pd += __shfl_down(pd, off);
    }
    if (lane == 0) {
      alp_s[w * 4 + h] = ps;
      alp_d[w * 4 + h] = pd;
    }
  }
}

// ---------------- MFMA bf16 GEMM + fused alpha epilogue (layers 2,3) ----------------

template <int KDIM>
__global__ __launch_bounds__(256) void mfma_gemm_alpha_kernel(
    const unsigned short* __restrict__ A, const unsigned short* __restrict__ Bt,
    unsigned short* __restrict__ C_bf, const float* __restrict__ a_src,
    const float* __restrict__ a_dst, float* __restrict__ alp_s,
    float* __restrict__ alp_d, int M, int Nc) {
  __shared__ unsigned short As[64][40];
  __shared__ unsigned short Bs[64][40];
  int t = threadIdx.x;
  int wave = t >> 6, lane = t & 63;
  int m_frag = lane & 15, quad = lane >> 4;
  int row0 = blockIdx.y * 64, col0 = blockIdx.x * 64;
  int lr = t >> 2;
  int lk = (t & 3) * 8;
  floatx4 acc[4];
  #pragma unroll
  for (int c = 0; c < 4; ++c) acc[c] = (floatx4){0.f, 0.f, 0.f, 0.f};

  for (int k0 = 0; k0 < KDIM; k0 += 32) {
    int gr = row0 + lr;
    short8 av = {0, 0, 0, 0, 0, 0, 0, 0};
    if (gr < M) av = *(const short8*)(A + (size_t)gr * KDIM + k0 + lk);
    *(short8*)(&As[lr][lk]) = av;
    short8 bv = *(const short8*)(Bt + (size_t)(col0 + lr) * KDIM + k0 + lk);
    *(short8*)(&Bs[lr][lk]) = bv;
    __syncthreads();
    short8 a = *(const short8*)(&As[wave * 16 + m_frag][quad * 8]);
    #pragma unroll
    for (int c = 0; c < 4; ++c) {
      short8 b = *(const short8*)(&Bs[c * 16 + m_frag][quad * 8]);
      acc[c] = __builtin_amdgcn_mfma_f32_16x16x32_bf16(a, b, acc[c], 0, 0, 0);
    }
    __syncthreads();
  }

  int H = Nc >> 6;
  int head = blockIdx.x;
  float ps[4] = {}, pd[4] = {};
  #pragma unroll
  for (int c = 0; c < 4; ++c) {
    float asv = a_src[head * 64 + c * 16 + m_frag];
    float adv = a_dst[head * 64 + c * 16 + m_frag];
    #pragma unroll
    for (int i = 0; i < 4; ++i) {
      ps[i] += acc[c][i] * asv;
      pd[i] += acc[c][i] * adv;
    }
  }
  #pragma unroll
  for (int off = 1; off < 16; off <<= 1) {
    #pragma unroll
    for (int i = 0; i < 4; ++i) {
      ps[i] += __shfl_xor(ps[i], off);
      pd[i] += __shfl_xor(pd[i], off);
    }
  }
  #pragma unroll
  for (int c = 0; c < 4; ++c) {
    #pragma unroll
    for (int i = 0; i < 4; ++i) {
      int gr = row0 + wave * 16 + quad * 4 + i;
      if (gr < M) C_bf[(size_t)gr * Nc + col0 + c * 16 + m_frag] = bf16_rne(acc[c][i]);
    }
  }
  if (m_frag == 0) {
    #pragma unroll
    for (int i = 0; i < 4; ++i) {
      int gr = row0 + wave * 16 + quad * 4 + i;
      if (gr < M) {
        alp_s[gr * H + head] = ps[i];
        alp_d[gr * H + head] = pd[i];
      }
    }
  }
}

// ---------------- MFMA GEMM, per-head (K=64, strided A) + bias + ELU, bf16 out ------
// blockIdx.x = head: A-tile cols [head*64,+64) of LDA=256; Bt = Bt1 [256][64].

__global__ __launch_bounds__(256) void mfma_gemm_be_kernel(
    const unsigned short* __restrict__ A, const unsigned short* __restrict__ Bt,
    const float* __restrict__ bias, unsigned short* __restrict__ C_bf, int M) {
  __shared__ unsigned short As[64][40];
  __shared__ unsigned short Bs[64][40];
  int t = threadIdx.x;
  int wave = t >> 6, lane = t & 63;
  int m_frag = lane & 15, quad = lane >> 4;
  int row0 = blockIdx.y * 64, col0 = blockIdx.x * 64;
  int lr = t >> 2;
  int lk = (t & 3) * 8;
  floatx4 acc[4];
  #pragma unroll
  for (int c = 0; c < 4; ++c) acc[c] = (floatx4){0.f, 0.f, 0.f, 0.f};

  for (int k0 = 0; k0 < 64; k0 += 32) {
    int gr = row0 + lr;
    short8 av = {0, 0, 0, 0, 0, 0, 0, 0};
    if (gr < M) av = *(const short8*)(A + (size_t)gr * 256 + col0 + k0 + lk);
    *(short8*)(&As[lr][lk]) = av;
    short8 bv = *(const short8*)(Bt + (size_t)(col0 + lr) * 64 + k0 + lk);
    *(short8*)(&Bs[lr][lk]) = bv;
    __syncthreads();
    short8 a = *(const short8*)(&As[wave * 16 + m_frag][quad * 8]);
    #pragma unroll
    for (int c = 0; c < 4; ++c) {
      short8 b = *(const short8*)(&Bs[c * 16 + m_frag][quad * 8]);
      acc[c] = __builtin_amdgcn_mfma_f32_16x16x32_bf16(a, b, acc[c], 0, 0, 0);
    }
    __syncthreads();
  }
  #pragma unroll
  for (int c = 0; c < 4; ++c) {
    float bv = bias[col0 + c * 16 + m_frag];
    #pragma unroll
    for (int i = 0; i < 4; ++i) {
      int gr = row0 + wave * 16 + quad * 4 + i;
      if (gr < M) C_bf[(size_t)gr * 256 + col0 + c * 16 + m_frag] = bf16_rne(elu_f(acc[c][i] + bv));
    }
  }
}

// ---------------- layer-1 fused softmax + INPUT-side aggregate ----------------------
// Gathers 64-dim h rows (128 B), accumulates 4 head-weighted sums.
// Out: agg_bf[n][h*64+k].  slot = t>>3 (32 slots), l = t&7 (8 ch each).

__global__ __launch_bounds__(256) void softagg_in_kernel(
    const int* __restrict__ row_ptr, const int* __restrict__ csr_eid,
    const int* __restrict__ src_arr, const float* __restrict__ ea,
    const float* __restrict__ alp_s, const float* __restrict__ alp_d,
    const float* __restrict__ proj, const unsigned short* __restrict__ h_bf,
    unsigned short* __restrict__ agg_bf) {
  constexpr int CHUNK = 256;
  __shared__ float lds_w[4][CHUNK];
  __shared__ int lds_src[CHUNK];
  __shared__ float sh_r[4];
  __shared__ float sh_inv[4];
  __shared__ float red[4 * 256];

  int n = blockIdx.x;
  int t = threadIdx.x;
  int wave = t >> 6, lane = t & 63;
  int slot = t >> 3, l = t & 7;
  int s0 = row_ptr[n], s1 = row_ptr[n + 1];

  float m_run = -INFINITY, s_run = 0.f;
  float acc[4][8] = {};
  float adv = alp_d[n * 4 + wave];
  float p0 = proj[0 * 4 + wave], p1 = proj[1 * 4 + wave], p2 = proj[2 * 4 + wave];

  for (int c0 = s0; c0 < s1; c0 += CHUNK) {
    int cend = min(s1, c0 + CHUNK);
    {
      int h = wave;
      float cm = -INFINITY;
      for (int i = c0 + lane; i < cend; i += 64) {
        int eid = csr_eid[i];
        int s = src_arr[eid];
        if (h == 0) lds_src[i - c0] = s;
        float a = alp_s[s * 4 + h] + adv
                + ea[eid * 3 + 0] * p0 + ea[eid * 3 + 1] * p1 + ea[eid * 3 + 2] * p2;
        a = a > 0.f ? a : 0.2f * a;
        lds_w[h][i - c0] = a;
        cm = fmaxf(cm, a);
      }
      #pragma unroll
      for (int off = 1; off < 64; off <<= 1) cm = fmaxf(cm, __shfl_xor(cm, off));
      float m_new = fmaxf(m_run, cm);
      float r = __expf(m_run - m_new);
      float se = 0.f;
      for (int i = c0 + lane; i < cend; i += 64) {
        float w = __expf(lds_w[h][i - c0] - m_new);
        lds_w[h][i - c0] = w;
        se += w;
      }
      #pragma unroll
      for (int off = 1; off < 64; off <<= 1) se += __shfl_xor(se, off);
      s_run = s_run * r + se;
      m_run = m_new;
      if (lane == 0) sh_r[h] = r;
    }
    __syncthreads();
    float r0 = sh_r[0], r1 = sh_r[1], r2 = sh_r[2], r3 = sh_r[3];
    #pragma unroll
    for (int j = 0; j < 8; ++j) {
      acc[0][j] *= r0; acc[1][j] *= r1; acc[2][j] *= r2; acc[3][j] *= r3;
    }
    for (int i = c0 + slot; i < cend; i += 32) {
      int s = lds_src[i - c0];
      float w0 = lds_w[0][i - c0], w1 = lds_w[1][i - c0];
      float w2 = lds_w[2][i - c0], w3 = lds_w[3][i - c0];
      short8 v = *(const short8*)(h_bf + (size_t)s * 64 + l * 8);
      #pragma unroll
      for (int j = 0; j < 8; ++j) {
        float f = bf_to_f((unsigned short)v[j]);
        acc[0][j] += f * w0; acc[1][j] += f * w1; acc[2][j] += f * w2; acc[3][j] += f * w3;
      }
    }
    __syncthreads();
  }
  if (lane == 0) sh_inv[wave] = 1.0f / (s_run + 1e-16f);
  __syncthreads();
  float i0 = sh_inv[0], i1 = sh_inv[1], i2 = sh_inv[2], i3 = sh_inv[3];
  #pragma unroll
  for (int j = 0; j < 8; ++j) {
    acc[0][j] *= i0; acc[1][j] *= i1; acc[2][j] *= i2; acc[3][j] *= i3;
  }
  // reduce 8 slots within wave
  #pragma unroll
  for (int off = 8; off < 64; off <<= 1) {
    #pragma unroll
    for (int h = 0; h < 4; ++h) {
      #pragma unroll
      for (int j = 0; j < 8; ++j) acc[h][j] += __shfl_xor(acc[h][j], off);
    }
  }
  if (lane < 8) {
    #pragma unroll
    for (int h = 0; h < 4; ++h) {
      #pragma unroll
      for (int j = 0; j < 8; ++j) red[wave * 256 + h * 64 + swz(l * 8 + j)] = acc[h][j];
    }
  }
  __syncthreads();
  int hh = t >> 6, cc = t & 63;
  int pos = hh * 64 + swz(cc);
  float a = red[0 * 256 + pos] + red[1 * 256 + pos] + red[2 * 256 + pos] + red[3 * 256 + pos];
  agg_bf[(size_t)n * 256 + t] = bf16_rne(a);
}

// ---------------- output-side fused softmax + aggregate (layers 2,3) ----------------

template <int HC, bool APPLY_ELU, bool OUT_BF>
__global__ __launch_bounds__(256) void softagg_kernel(
    const int* __restrict__ row_ptr, const int* __restrict__ csr_eid,
    const int* __restrict__ src_arr, const float* __restrict__ ea,
    const float* __restrict__ alp_s, const float* __restrict__ alp_d,
    const float* __restrict__ proj, const unsigned short* __restrict__ xh_bf,
    const float* __restrict__ bias, float* __restrict__ out,
    unsigned short* __restrict__ out_bf) {
  constexpr int H = HC / 64;
  constexpr int CHUNK = 256;
  constexpr int L = HC / 8;    // threads per edge slot
  constexpr int S = 256 / L;   // edge slots
  __shared__ float lds_w[H][CHUNK];
  __shared__ int lds_src[CHUNK];
  __shared__ float sh_r[H];
  __shared__ float sh_inv[H];
  __shared__ float red[4 * HC];

  int n = blockIdx.x;
  int t = threadIdx.x;
  int wave = t >> 6, lane = t & 63;
  int slot = t / L, l = t % L;
  int head2 = (8 * l) >> 6;
  int s0 = row_ptr[n], s1 = row_ptr[n + 1];

  float m_run = -INFINITY, s_run = 0.f;
  float acc[8] = {};
  float adv = 0.f, p0 = 0.f, p1 = 0.f, p2 = 0.f;
  if (wave < H) {
    adv = alp_d[n * H + wave];
    p0 = proj[0 * H + wave];
    p1 = proj[1 * H + wave];
    p2 = proj[2 * H + wave];
  }

  for (int c0 = s0; c0 < s1; c0 += CHUNK) {
    int cend = min(s1, c0 + CHUNK);
    if (wave < H) {
      int h = wave;
      float cm = -INFINITY;
      for (int i = c0 + lane; i < cend; i += 64) {
        int eid = csr_eid[i];
        int s = src_arr[eid];
        if (h == 0) lds_src[i - c0] = s;
        float a = alp_s[s * H + h] + adv
                + ea[eid * 3 + 0] * p0 + ea[eid * 3 + 1] * p1 + ea[eid * 3 + 2] * p2;
        a = a > 0.f ? a : 0.2f * a;
        lds_w[h][i - c0] = a;
        cm = fmaxf(cm, a);
      }
      #pragma unroll
      for (int off = 1; off < 64; off <<= 1) cm = fmaxf(cm, __shfl_xor(cm, off));
      float m_new = fmaxf(m_run, cm);
      float r = __expf(m_run - m_new);
      float se = 0.f;
      for (int i = c0 + lane; i < cend; i += 64) {
        float w = __expf(lds_w[h][i - c0] - m_new);
        lds_w[h][i - c0] = w;
        se += w;
      }
      #pragma unroll
      for (int off = 1; off < 64; off <<= 1) se += __shfl_xor(se, off);
      s_run = s_run * r + se;
      m_run = m_new;
      if (lane == 0) sh_r[h] = r;
    }
    __syncthreads();
    float rr = sh_r[head2];
    #pragma unroll
    for (int j = 0; j < 8; ++j) acc[j] *= rr;
    for (int i = c0 + slot; i < cend; i += S) {
      float w = lds_w[head2][i - c0];
      int s = lds_src[i - c0];
      short8 v = *(const short8*)(xh_bf + (size_t)s * HC + l * 8);
      #pragma unroll
      for (int j = 0; j < 8; ++j) acc[j] += bf_to_f((unsigned short)v[j]) * w;
    }
    __syncthreads();
  }
  if (wave < H && lane == 0) sh_inv[wave] = 1.0f / (s_run + 1e-16f);
  __syncthreads();
  float inv = sh_inv[head2];
  #pragma unroll
  for (int j = 0; j < 8; ++j) acc[j] *= inv;
  // reduce slots within wave (slots stride L lanes; 64/L slots per wave)
  #pragma unroll
  for (int off = L; off < 64; off <<= 1) {
    #pragma unroll
    for (int j = 0; j < 8; ++j) acc[j] += __shfl_xor(acc[j], off);
  }
  if (lane < L) {
    #pragma unroll
    for (int j = 0; j < 8; ++j) red[wave * HC + swz(lane * 8 + j)] = acc[j];
  }
  __syncthreads();
  if (t < HC) {
    int pos = swz(t);
    float a = red[0 * HC + pos] + red[1 * HC + pos] + red[2 * HC + pos] + red[3 * HC + pos];
    a += bias[t];
    if (APPLY_ELU) a = elu_f(a);
    if (OUT_BF) out_bf[(size_t)n * HC + t] = bf16_rne(a);
    else out[(size_t)n * HC + t] = a;
  }
}

// ---------------- classifier: wave per node, 64 -> softmax(4) ----------------

__global__ void classifier_kernel(const float* __restrict__ h, const float* __restrict__ Wc,
                                  const float* __restrict__ bc, float* __restrict__ out,
                                  int n_nodes) {
  int gid = blockIdx.x * 256 + threadIdx.x;
  int w = gid >> 6, lane = gid & 63;
  if (w >= n_nodes) return;
  float hv = h[w * 64 + lane];
  float p0 = hv * Wc[lane * 4 + 0];
  float p1 = hv * Wc[lane * 4 + 1];
  float p2 = hv * Wc[lane * 4 + 2];
  float p3 = hv * Wc[lane * 4 + 3];
  for (int off = 32; off; off >>= 1) {
    p0 += __shfl_down(p0, off);
    p1 += __shfl_down(p1, off);
    p2 += __shfl_down(p2, off);
    p3 += __shfl_down(p3, off);
  }
  if (lane == 0) {
    p0 += bc[0]; p1 += bc[1]; p2 += bc[2]; p3 += bc[3];
    float mx = fmaxf(fmaxf(p0, p1), fmaxf(p2, p3));
    float e0 = __expf(p0 - mx), e1 = __expf(p1 - mx), e2 = __expf(p2 - mx), e3 = __expf(p3 - mx);
    float inv = 1.f / (e0 + e1 + e2 + e3);
    out[w * 4 + 0] = e0 * inv;
    out[w * 4 + 1] = e1 * inv;
    out[w * 4 + 2] = e2 * inv;
    out[w * 4 + 3] = e3 * inv;
  }
}

// ---------------- host ----------------

extern "C" void kernel_launch(void* const* d_in, const int* in_sizes, int n_in,
                              void* d_out, int out_size, void* d_ws, size_t ws_size,
                              hipStream_t stream) {
  const float* x   = (const float*)d_in[0];
  const int*   ei  = (const int*)d_in[1];
  const float* ea  = (const float*)d_in[2];
  const float* Wp  = (const float*)d_in[3];
  const float* bp  = (const float*)d_in[4];
  const float* W1  = (const float*)d_in[5];
  const float* We1 = (const float*)d_in[6];
  const float* as1 = (const float*)d_in[7];
  const float* ad1 = (const float*)d_in[8];
  const float* ae1 = (const float*)d_in[9];
  const float* b1  = (const float*)d_in[10];
  const float* W2  = (const float*)d_in[11];
  const float* We2 = (const float*)d_in[12];
  const float* as2 = (const float*)d_in[13];
  const float* ad2 = (const float*)d_in[14];
  const float* ae2 = (const float*)d_in[15];
  const float* b2  = (const float*)d_in[16];
  const float* W3  = (const float*)d_in[17];
  const float* We3 = (const float*)d_in[18];
  const float* as3 = (const float*)d_in[19];
  const float* ad3 = (const float*)d_in[20];
  const float* ae3 = (const float*)d_in[21];
  const float* b3  = (const float*)d_in[22];
  const float* Wc  = (const float*)d_in[23];
  const float* bc  = (const float*)d_in[24];
  float* out = (float*)d_out;

  const int* src = ei;
  const int* dst = ei + N_EDGES;

  char* wptr = (char*)d_ws;
  auto alloc = [&](size_t bytes) {
    char* p = wptr;
    wptr += (bytes + 255) & ~(size_t)255;
    return p;
  };
  int*            cnt      = (int*)alloc((size_t)N_NODES * 4);
  int*            row_ptr  = (int*)alloc((size_t)(N_NODES + 1) * 4);
  int*            row_next = (int*)alloc((size_t)N_NODES * 4);
  int*            csr_eid  = (int*)alloc((size_t)N_EDGES * 4);
  unsigned short* hH_bf    = (unsigned short*)alloc((size_t)N_NODES * 64 * 2);
  unsigned short* hA_bf    = (unsigned short*)alloc((size_t)N_NODES * 256 * 2);
  unsigned short* hX_bf    = (unsigned short*)alloc((size_t)N_NODES * 256 * 2);
  float*          hC       = (float*)alloc((size_t)N_NODES * 64 * 4);
  float*          alp_s    = (float*)alloc((size_t)N_NODES * 4 * 4);
  float*          alp_d    = (float*)alloc((size_t)N_NODES * 4 * 4);
  float*          proj     = (float*)alloc(32 * 4);
  float*          u_s      = (float*)alloc(256 * 4);
  float*          u_d      = (float*)alloc(256 * 4);
  unsigned short* Bt1      = (unsigned short*)alloc((size_t)64 * 256 * 2);
  unsigned short* Bt2      = (unsigned short*)alloc((size_t)256 * 256 * 2);
  unsigned short* Bt3      = (unsigned short*)alloc((size_t)256 * 64 * 2);

  // ---- CSR build ----
  zero_int_kernel<<<(N_NODES + 255) / 256, 256, 0, stream>>>(cnt, N_NODES);
  hist_kernel<<<(N_EDGES + 255) / 256, 256, 0, stream>>>(dst, cnt, N_EDGES);
  scan_kernel<<<1, 1024, 0, stream>>>(cnt, row_ptr, row_next, N_NODES);
  fill_kernel<<<(N_EDGES + 255) / 256, 256, 0, stream>>>(dst, row_next, csr_eid, N_EDGES);

  // ---- prep ----
  wt_all_kernel<<<(98304 + 255) / 256, 256, 0, stream>>>(W1, W2, W3, Bt1, Bt2, Bt3);
  prep_kernel<<<1, 512, 0, stream>>>(W1, as1, ad1, We1, ae1, We2, ae2, We3, ae3, u_s, u_d, proj);

  // ---- input projection + layer-1 alpha ----
  in_proj_alpha_kernel<<<(N_NODES * 64 + 255) / 256, 256, 0, stream>>>(x, Wp, bp, u_s, u_d,
                                                                       hH_bf, alp_s, alp_d, N_NODES);

  dim3 g256(4, (N_NODES + 63) / 64);
  dim3 g64(1, (N_NODES + 63) / 64);

  // ---- layer 1: input-side aggregate (64-dim gather) then per-head W1 + bias + ELU ----
  softagg_in_kernel<<<N_NODES, 256, 0, stream>>>(row_ptr, csr_eid, src, ea, alp_s, alp_d,
                                                 proj + 0, hH_bf, hX_bf);
  mfma_gemm_be_kernel<<<g256, 256, 0, stream>>>(hX_bf, Bt1, b1, hA_bf, N_NODES);

  // ---- layer 2: 256 -> 4x64, ELU ----
  mfma_gemm_alpha_kernel<256><<<g256, 256, 0, stream>>>(hA_bf, Bt2, hX_bf, as2, ad2,
                                                        alp_s, alp_d, N_NODES, 256);
  softagg_kernel<256, true, true><<<N_NODES, 256, 0, stream>>>(row_ptr, csr_eid, src, ea,
                                                               alp_s, alp_d, proj + 12, hX_bf,
                                                               b2, nullptr, hA_bf);

  // ---- layer 3: 256 -> 1x64, no ELU ----
  mfma_gemm_alpha_kernel<256><<<g64, 256, 0, stream>>>(hA_bf, Bt3, hX_bf, as3, ad3,
                                                       alp_s, alp_d, N_NODES, 64);
  softagg_kernel<64, false, false><<<N_NODES, 256, 0, stream>>>(row_ptr, csr_eid, src, ea,
                                                                alp_s, alp_d, proj + 24, hX_bf,
                                                                b3, hC, nullptr);

  // ---- classifier + softmax ----
  classifier_kernel<<<N_NODES * 64 / 256, 256, 0, stream>>>(hC, Wc, bc, out, N_NODES);
}

// Round 7
// 423.057 us; speedup vs baseline: 1.1705x; 1.1705x over previous
//
#include <hip/hip_runtime.h>
#include <math.h>

#define N_NODES 20000
#define N_EDGES 640000

typedef __attribute__((ext_vector_type(8))) short short8;
typedef __attribute__((ext_vector_type(4))) float floatx4;

__device__ __forceinline__ float elu_f(float v) { return v > 0.f ? v : expm1f(v); }

__device__ __forceinline__ unsigned short bf16_rne(float f) {
  union { float f; unsigned u; } v;
  v.f = f;
  unsigned r = v.u + 0x7FFF + ((v.u >> 16) & 1);
  return (unsigned short)(r >> 16);
}

__device__ __forceinline__ float bf_to_f(unsigned short u) {
  union { unsigned u; float f; } v;
  v.u = (unsigned)u << 16;
  return v.f;
}

// bank-swizzle within 8-element groups: writer (8-elem strided) and reader both conflict-free
__device__ __forceinline__ int swz(int c) {
  return (c & ~7) | ((((c & 7) + ((c >> 3) >> 2))) & 7);
}

// ---------------- CSR build ----------------

__global__ void zero_int_kernel(int* p, int n) {
  int i = blockIdx.x * 256 + threadIdx.x;
  if (i < n) p[i] = 0;
}

__global__ void hist_kernel(const int* __restrict__ dst, int* __restrict__ cnt, int ne) {
  int e = blockIdx.x * 256 + threadIdx.x;
  if (e < ne) atomicAdd(&cnt[dst[e]], 1);
}

__global__ __launch_bounds__(1024) void scan_kernel(const int* __restrict__ cnt,
                                                    int* __restrict__ row_ptr,
                                                    int* __restrict__ row_next, int n) {
  __shared__ int part[1024];
  int t = threadIdx.x;
  int per = (n + 1023) / 1024;
  int base = t * per;
  int local = 0;
  for (int i = 0; i < per; ++i) {
    int idx = base + i;
    if (idx < n) local += cnt[idx];
  }
  part[t] = local;
  __syncthreads();
  for (int off = 1; off < 1024; off <<= 1) {
    int v = (t >= off) ? part[t - off] : 0;
    __syncthreads();
    part[t] += v;
    __syncthreads();
  }
  int prefix = (t == 0) ? 0 : part[t - 1];
  for (int i = 0; i < per; ++i) {
    int idx = base + i;
    if (idx < n) {
      row_ptr[idx] = prefix;
      row_next[idx] = prefix;
      prefix += cnt[idx];
    }
  }
  if (t == 1023) row_ptr[n] = part[1023];
}

__global__ void fill_kernel(const int* __restrict__ dst, int* __restrict__ row_next,
                            int* __restrict__ csr_eid, int ne) {
  int e = blockIdx.x * 256 + threadIdx.x;
  if (e >= ne) return;
  int pos = atomicAdd(&row_next[dst[e]], 1);
  csr_eid[pos] = e;
}

// ---------------- weight cast+transpose: Bt[n][k] = bf16(W[k][n]) ----------------

__global__ void wt_all_kernel(const float* __restrict__ W1, const float* __restrict__ W2,
                              const float* __restrict__ W3, unsigned short* __restrict__ Bt1,
                              unsigned short* __restrict__ Bt2, unsigned short* __restrict__ Bt3) {
  int idx = blockIdx.x * 256 + threadIdx.x;
  const float* W; unsigned short* Bt; int K, Nc, local;
  if (idx < 16384)      { W = W1; Bt = Bt1; K = 64;  Nc = 256; local = idx; }
  else if (idx < 81920) { W = W2; Bt = Bt2; K = 256; Nc = 256; local = idx - 16384; }
  else if (idx < 98304) { W = W3; Bt = Bt3; K = 256; Nc = 64;  local = idx - 81920; }
  else return;
  int k = local / Nc, n = local - k * Nc;
  Bt[(size_t)n * K + k] = bf16_rne(W[local]);
}

// ---------------- aeproj (all 3 layers) -----------------------------------------
// proj[0..11] layer1 (d*4+h), proj[12..23] layer2, proj[24..26] layer3

__global__ void aeproj_all_kernel(const float* __restrict__ We1, const float* __restrict__ ae1,
                                  const float* __restrict__ We2, const float* __restrict__ ae2,
                                  const float* __restrict__ We3, const float* __restrict__ ae3,
                                  float* __restrict__ proj) {
  int t = threadIdx.x;
  if (t < 12) {
    int d = t >> 2, h = t & 3;
    float s = 0.f;
    for (int c = 0; c < 64; ++c) s += We1[d * 256 + h * 64 + c] * ae1[h * 64 + c];
    proj[t] = s;
  } else if (t < 24) {
    int u = t - 12; int d = u >> 2, h = u & 3;
    float s = 0.f;
    for (int c = 0; c < 64; ++c) s += We2[d * 256 + h * 64 + c] * ae2[h * 64 + c];
    proj[12 + u] = s;
  } else if (t < 27) {
    int d = t - 24;
    float s = 0.f;
    for (int c = 0; c < 64; ++c) s += We3[d * 64 + c] * ae3[c];
    proj[24 + d] = s;
  }
}

// ---------------- edge prep: CSR-order src + per-layer edge-dot planes --------------
// edot planes: [0..3] layer1 (h), [4..7] layer2, [8] layer3. All coalesced writes.

__global__ void edge_prep_kernel(const int* __restrict__ csr_eid, const int* __restrict__ src,
                                 const float* __restrict__ ea, const float* __restrict__ proj,
                                 int* __restrict__ csr_src, float* __restrict__ edot) {
  int i = blockIdx.x * 256 + threadIdx.x;
  if (i >= N_EDGES) return;
  int eid = csr_eid[i];
  csr_src[i] = src[eid];
  float e0 = ea[eid * 3 + 0], e1 = ea[eid * 3 + 1], e2 = ea[eid * 3 + 2];
  #pragma unroll
  for (int h = 0; h < 4; ++h)
    edot[(size_t)h * N_EDGES + i] = e0 * proj[h] + e1 * proj[4 + h] + e2 * proj[8 + h];
  #pragma unroll
  for (int h = 0; h < 4; ++h)
    edot[(size_t)(4 + h) * N_EDGES + i] = e0 * proj[12 + h] + e1 * proj[16 + h] + e2 * proj[20 + h];
  edot[(size_t)8 * N_EDGES + i] = e0 * proj[24] + e1 * proj[25] + e2 * proj[26];
}

// ---------------- input projection (emit bf16) ----------------

__global__ void in_proj_kernel(const float* __restrict__ x, const float* __restrict__ Wp,
                               const float* __restrict__ bp, unsigned short* __restrict__ h_bf,
                               int n) {
  int i = blockIdx.x * 256 + threadIdx.x;
  if (i >= n * 64) return;
  int node = i >> 6, c = i & 63;
  float v = x[node * 2] * Wp[c] + x[node * 2 + 1] * Wp[64 + c] + bp[c];
  h_bf[i] = bf16_rne(elu_f(v));
}

// ---------------- MFMA bf16 GEMM + fused alpha epilogue ----------------------------

template <int KDIM>
__global__ __launch_bounds__(256) void mfma_gemm_alpha_kernel(
    const unsigned short* __restrict__ A, const unsigned short* __restrict__ Bt,
    unsigned short* __restrict__ C_bf, const float* __restrict__ a_src,
    const float* __restrict__ a_dst, float* __restrict__ alp_s,
    float* __restrict__ alp_d, int M, int Nc) {
  __shared__ unsigned short As[64][40];
  __shared__ unsigned short Bs[64][40];
  int t = threadIdx.x;
  int wave = t >> 6, lane = t & 63;
  int m_frag = lane & 15, quad = lane >> 4;
  int row0 = blockIdx.y * 64, col0 = blockIdx.x * 64;
  int lr = t >> 2;
  int lk = (t & 3) * 8;
  floatx4 acc[4];
  #pragma unroll
  for (int c = 0; c < 4; ++c) acc[c] = (floatx4){0.f, 0.f, 0.f, 0.f};

  for (int k0 = 0; k0 < KDIM; k0 += 32) {
    int gr = row0 + lr;
    short8 av = {0, 0, 0, 0, 0, 0, 0, 0};
    if (gr < M) av = *(const short8*)(A + (size_t)gr * KDIM + k0 + lk);
    *(short8*)(&As[lr][lk]) = av;
    short8 bv = *(const short8*)(Bt + (size_t)(col0 + lr) * KDIM + k0 + lk);
    *(short8*)(&Bs[lr][lk]) = bv;
    __syncthreads();
    short8 a = *(const short8*)(&As[wave * 16 + m_frag][quad * 8]);
    #pragma unroll
    for (int c = 0; c < 4; ++c) {
      short8 b = *(const short8*)(&Bs[c * 16 + m_frag][quad * 8]);
      acc[c] = __builtin_amdgcn_mfma_f32_16x16x32_bf16(a, b, acc[c], 0, 0, 0);
    }
    __syncthreads();
  }

  int H = Nc >> 6;
  int head = blockIdx.x;
  float ps[4] = {}, pd[4] = {};
  #pragma unroll
  for (int c = 0; c < 4; ++c) {
    float asv = a_src[head * 64 + c * 16 + m_frag];
    float adv = a_dst[head * 64 + c * 16 + m_frag];
    #pragma unroll
    for (int i = 0; i < 4; ++i) {
      ps[i] += acc[c][i] * asv;
      pd[i] += acc[c][i] * adv;
    }
  }
  #pragma unroll
  for (int off = 1; off < 16; off <<= 1) {
    #pragma unroll
    for (int i = 0; i < 4; ++i) {
      ps[i] += __shfl_xor(ps[i], off);
      pd[i] += __shfl_xor(pd[i], off);
    }
  }
  #pragma unroll
  for (int c = 0; c < 4; ++c) {
    #pragma unroll
    for (int i = 0; i < 4; ++i) {
      int gr = row0 + wave * 16 + quad * 4 + i;
      if (gr < M) C_bf[(size_t)gr * Nc + col0 + c * 16 + m_frag] = bf16_rne(acc[c][i]);
    }
  }
  if (m_frag == 0) {
    #pragma unroll
    for (int i = 0; i < 4; ++i) {
      int gr = row0 + wave * 16 + quad * 4 + i;
      if (gr < M) {
        alp_s[gr * H + head] = ps[i];
        alp_d[gr * H + head] = pd[i];
      }
    }
  }
}

// ---------------- fused softmax + aggregate: one block per dst node -----------------
// Phase 1 (wave h): alpha from coalesced csr_src/edot + alp_s gather; online (m,s).
// Phase 2 (all): 2-way unrolled weighted gather of xh rows; swizzled LDS reduction.

template <int HC, bool APPLY_ELU, bool OUT_BF>
__global__ __launch_bounds__(256) void softagg_kernel(
    const int* __restrict__ row_ptr, const int* __restrict__ csr_src,
    const float* __restrict__ edot, const float* __restrict__ alp_s,
    const float* __restrict__ alp_d, const unsigned short* __restrict__ xh_bf,
    const float* __restrict__ bias, float* __restrict__ out,
    unsigned short* __restrict__ out_bf) {
  constexpr int H = HC / 64;
  constexpr int CHUNK = 256;
  constexpr int L = HC / 8;    // threads per edge slot
  constexpr int S = 256 / L;   // edge slots
  __shared__ float lds_w[H][CHUNK];
  __shared__ int lds_src[CHUNK];
  __shared__ float sh_r[H];
  __shared__ float sh_inv[H];
  __shared__ float red[4 * HC];

  int n = blockIdx.x;
  int t = threadIdx.x;
  int wave = t >> 6, lane = t & 63;
  int slot = t / L, l = t % L;
  int head2 = (8 * l) >> 6;
  int s0 = row_ptr[n], s1 = row_ptr[n + 1];

  float m_run = -INFINITY, s_run = 0.f;
  float acc[8] = {};
  float adv = 0.f;
  const float* __restrict__ edot_h = edot + (size_t)wave * N_EDGES;
  if (wave < H) adv = alp_d[n * H + wave];

  for (int c0 = s0; c0 < s1; c0 += CHUNK) {
    int cend = min(s1, c0 + CHUNK);
    if (wave < H) {
      int h = wave;
      float cm = -INFINITY;
      for (int i = c0 + lane; i < cend; i += 64) {
        int s = csr_src[i];
        if (h == 0) lds_src[i - c0] = s;
        float a = alp_s[s * H + h] + adv + edot_h[i];
        a = a > 0.f ? a : 0.2f * a;
        lds_w[h][i - c0] = a;
        cm = fmaxf(cm, a);
      }
      #pragma unroll
      for (int off = 1; off < 64; off <<= 1) cm = fmaxf(cm, __shfl_xor(cm, off));
      float m_new = fmaxf(m_run, cm);
      float r = __expf(m_run - m_new);
      float se = 0.f;
      for (int i = c0 + lane; i < cend; i += 64) {
        float w = __expf(lds_w[h][i - c0] - m_new);
        lds_w[h][i - c0] = w;
        se += w;
      }
      #pragma unroll
      for (int off = 1; off < 64; off <<= 1) se += __shfl_xor(se, off);
      s_run = s_run * r + se;
      m_run = m_new;
      if (lane == 0) sh_r[h] = r;
    }
    __syncthreads();
    float rr = sh_r[head2];
    #pragma unroll
    for (int j = 0; j < 8; ++j) acc[j] *= rr;
    // 2-way unrolled gather: two loads in flight per iteration
    int i = c0 + slot;
    for (; i + S < cend; i += 2 * S) {
      int sA = lds_src[i - c0];
      int sB = lds_src[i - c0 + S];
      float wA = lds_w[head2][i - c0];
      float wB = lds_w[head2][i - c0 + S];
      short8 vA = *(const short8*)(xh_bf + (size_t)sA * HC + l * 8);
      short8 vB = *(const short8*)(xh_bf + (size_t)sB * HC + l * 8);
      #pragma unroll
      for (int j = 0; j < 8; ++j) acc[j] += bf_to_f((unsigned short)vA[j]) * wA;
      #pragma unroll
      for (int j = 0; j < 8; ++j) acc[j] += bf_to_f((unsigned short)vB[j]) * wB;
    }
    if (i < cend) {
      int s = lds_src[i - c0];
      float w = lds_w[head2][i - c0];
      short8 v = *(const short8*)(xh_bf + (size_t)s * HC + l * 8);
      #pragma unroll
      for (int j = 0; j < 8; ++j) acc[j] += bf_to_f((unsigned short)v[j]) * w;
    }
    __syncthreads();
  }
  if (wave < H && lane == 0) sh_inv[wave] = 1.0f / (s_run + 1e-16f);
  __syncthreads();
  float inv = sh_inv[head2];
  #pragma unroll
  for (int j = 0; j < 8; ++j) acc[j] *= inv;
  // reduce slots within wave (slots stride L lanes)
  #pragma unroll
  for (int off = L; off < 64; off <<= 1) {
    #pragma unroll
    for (int j = 0; j < 8; ++j) acc[j] += __shfl_xor(acc[j], off);
  }
  if (lane < L) {
    #pragma unroll
    for (int j = 0; j < 8; ++j) red[wave * HC + swz(lane * 8 + j)] = acc[j];
  }
  __syncthreads();
  if (t < HC) {
    int pos = swz(t);
    float a = red[0 * HC + pos] + red[1 * HC + pos] + red[2 * HC + pos] + red[3 * HC + pos];
    a += bias[t];
    if (APPLY_ELU) a = elu_f(a);
    if (OUT_BF) out_bf[(size_t)n * HC + t] = bf16_rne(a);
    else out[(size_t)n * HC + t] = a;
  }
}

// ---------------- classifier: wave per node, 64 -> softmax(4) ----------------

__global__ void classifier_kernel(const float* __restrict__ h, const float* __restrict__ Wc,
                                  const float* __restrict__ bc, float* __restrict__ out,
                                  int n_nodes) {
  int gid = blockIdx.x * 256 + threadIdx.x;
  int w = gid >> 6, lane = gid & 63;
  if (w >= n_nodes) return;
  float hv = h[w * 64 + lane];
  float p0 = hv * Wc[lane * 4 + 0];
  float p1 = hv * Wc[lane * 4 + 1];
  float p2 = hv * Wc[lane * 4 + 2];
  float p3 = hv * Wc[lane * 4 + 3];
  for (int off = 32; off; off >>= 1) {
    p0 += __shfl_down(p0, off);
    p1 += __shfl_down(p1, off);
    p2 += __shfl_down(p2, off);
    p3 += __shfl_down(p3, off);
  }
  if (lane == 0) {
    p0 += bc[0]; p1 += bc[1]; p2 += bc[2]; p3 += bc[3];
    float mx = fmaxf(fmaxf(p0, p1), fmaxf(p2, p3));
    float e0 = __expf(p0 - mx), e1 = __expf(p1 - mx), e2 = __expf(p2 - mx), e3 = __expf(p3 - mx);
    float inv = 1.f / (e0 + e1 + e2 + e3);
    out[w * 4 + 0] = e0 * inv;
    out[w * 4 + 1] = e1 * inv;
    out[w * 4 + 2] = e2 * inv;
    out[w * 4 + 3] = e3 * inv;
  }
}

// ---------------- host ----------------

extern "C" void kernel_launch(void* const* d_in, const int* in_sizes, int n_in,
                              void* d_out, int out_size, void* d_ws, size_t ws_size,
                              hipStream_t stream) {
  const float* x   = (const float*)d_in[0];
  const int*   ei  = (const int*)d_in[1];
  const float* ea  = (const float*)d_in[2];
  const float* Wp  = (const float*)d_in[3];
  const float* bp  = (const float*)d_in[4];
  const float* W1  = (const float*)d_in[5];
  const float* We1 = (const float*)d_in[6];
  const float* as1 = (const float*)d_in[7];
  const float* ad1 = (const float*)d_in[8];
  const float* ae1 = (const float*)d_in[9];
  const float* b1  = (const float*)d_in[10];
  const float* W2  = (const float*)d_in[11];
  const float* We2 = (const float*)d_in[12];
  const float* as2 = (const float*)d_in[13];
  const float* ad2 = (const float*)d_in[14];
  const float* ae2 = (const float*)d_in[15];
  const float* b2  = (const float*)d_in[16];
  const float* W3  = (const float*)d_in[17];
  const float* We3 = (const float*)d_in[18];
  const float* as3 = (const float*)d_in[19];
  const float* ad3 = (const float*)d_in[20];
  const float* ae3 = (const float*)d_in[21];
  const float* b3  = (const float*)d_in[22];
  const float* Wc  = (const float*)d_in[23];
  const float* bc  = (const float*)d_in[24];
  float* out = (float*)d_out;

  const int* src = ei;
  const int* dst = ei + N_EDGES;

  char* wptr = (char*)d_ws;
  auto alloc = [&](size_t bytes) {
    char* p = wptr;
    wptr += (bytes + 255) & ~(size_t)255;
    return p;
  };
  int*            cnt      = (int*)alloc((size_t)N_NODES * 4);
  int*            row_ptr  = (int*)alloc((size_t)(N_NODES + 1) * 4);
  int*            row_next = (int*)alloc((size_t)N_NODES * 4);
  int*            csr_eid  = (int*)alloc((size_t)N_EDGES * 4);
  int*            csr_src  = (int*)alloc((size_t)N_EDGES * 4);
  float*          edot     = (float*)alloc((size_t)9 * N_EDGES * 4);
  unsigned short* hA_bf    = (unsigned short*)alloc((size_t)N_NODES * 256 * 2);
  unsigned short* hX_bf    = (unsigned short*)alloc((size_t)N_NODES * 256 * 2);
  float*          hC       = (float*)alloc((size_t)N_NODES * 64 * 4);
  float*          alp_s    = (float*)alloc((size_t)N_NODES * 4 * 4);
  float*          alp_d    = (float*)alloc((size_t)N_NODES * 4 * 4);
  float*          proj     = (float*)alloc(32 * 4);
  unsigned short* Bt1      = (unsigned short*)alloc((size_t)64 * 256 * 2);
  unsigned short* Bt2      = (unsigned short*)alloc((size_t)256 * 256 * 2);
  unsigned short* Bt3      = (unsigned short*)alloc((size_t)256 * 64 * 2);

  // ---- CSR build ----
  zero_int_kernel<<<(N_NODES + 255) / 256, 256, 0, stream>>>(cnt, N_NODES);
  hist_kernel<<<(N_EDGES + 255) / 256, 256, 0, stream>>>(dst, cnt, N_EDGES);
  scan_kernel<<<1, 1024, 0, stream>>>(cnt, row_ptr, row_next, N_NODES);
  fill_kernel<<<(N_EDGES + 255) / 256, 256, 0, stream>>>(dst, row_next, csr_eid, N_EDGES);

  // ---- prep ----
  wt_all_kernel<<<(98304 + 255) / 256, 256, 0, stream>>>(W1, W2, W3, Bt1, Bt2, Bt3);
  aeproj_all_kernel<<<1, 64, 0, stream>>>(We1, ae1, We2, ae2, We3, ae3, proj);
  edge_prep_kernel<<<(N_EDGES + 255) / 256, 256, 0, stream>>>(csr_eid, src, ea, proj,
                                                              csr_src, edot);

  // ---- input projection (bf16) ----
  in_proj_kernel<<<N_NODES * 64 / 256, 256, 0, stream>>>(x, Wp, bp, hA_bf, N_NODES);

  dim3 g256(4, (N_NODES + 63) / 64);
  dim3 g64(1, (N_NODES + 63) / 64);

  // ---- layer 1: 64 -> 4x64, ELU ----
  mfma_gemm_alpha_kernel<64><<<g256, 256, 0, stream>>>(hA_bf, Bt1, hX_bf, as1, ad1,
                                                       alp_s, alp_d, N_NODES, 256);
  softagg_kernel<256, true, true><<<N_NODES, 256, 0, stream>>>(row_ptr, csr_src,
                                                               edot + (size_t)0 * N_EDGES,
                                                               alp_s, alp_d, hX_bf,
                                                               b1, nullptr, hA_bf);

  // ---- layer 2: 256 -> 4x64, ELU ----
  mfma_gemm_alpha_kernel<256><<<g256, 256, 0, stream>>>(hA_bf, Bt2, hX_bf, as2, ad2,
                                                        alp_s, alp_d, N_NODES, 256);
  softagg_kernel<256, true, true><<<N_NODES, 256, 0, stream>>>(row_ptr, csr_src,
                                                               edot + (size_t)4 * N_EDGES,
                                                               alp_s, alp_d, hX_bf,
                                                               b2, nullptr, hA_bf);

  // ---- layer 3: 256 -> 1x64, no ELU ----
  mfma_gemm_alpha_kernel<256><<<g64, 256, 0, stream>>>(hA_bf, Bt3, hX_bf, as3, ad3,
                                                       alp_s, alp_d, N_NODES, 64);
  softagg_kernel<64, false, false><<<N_NODES, 256, 0, stream>>>(row_ptr, csr_src,
                                                                edot + (size_t)8 * N_EDGES,
                                                                alp_s, alp_d, hX_bf,
                                                                b3, hC, nullptr);

  // ---- classifier + softmax ----
  classifier_kernel<<<N_NODES * 64 / 256, 256, 0, stream>>>(hC, Wc, bc, out, N_NODES);
}

// Round 8
// 396.329 us; speedup vs baseline: 1.2495x; 1.0674x over previous
//
#include <hip/hip_runtime.h>
#include <math.h>

#define N_NODES 20000
#define N_EDGES 640000

typedef __attribute__((ext_vector_type(8))) short short8;
typedef __attribute__((ext_vector_type(4))) float floatx4;
typedef __attribute__((ext_vector_type(2))) float float2v;

__device__ __forceinline__ float elu_f(float v) { return v > 0.f ? v : expm1f(v); }

__device__ __forceinline__ unsigned short bf16_rne(float f) {
  union { float f; unsigned u; } v;
  v.f = f;
  unsigned r = v.u + 0x7FFF + ((v.u >> 16) & 1);
  return (unsigned short)(r >> 16);
}

__device__ __forceinline__ float bf_to_f(unsigned short u) {
  union { unsigned u; float f; } v;
  v.u = (unsigned)u << 16;
  return v.f;
}

// unpack a dword holding two bf16 (lo = elem0, hi = elem1) into packed f32 pair
__device__ __forceinline__ float2v unpack_bf2(unsigned u) {
  union { unsigned u; float f; } lo, hi;
  lo.u = u << 16;
  hi.u = u & 0xffff0000u;
  return (float2v){lo.f, hi.f};
}

// bank-swizzle within 8-element groups (writer 8-strided and reader both conflict-free)
__device__ __forceinline__ int swz(int c) {
  return (c & ~7) | ((((c & 7) + ((c >> 3) >> 2))) & 7);
}

// ---------------- CSR build ----------------

__global__ void zero_int_kernel(int* p, int n) {
  int i = blockIdx.x * 256 + threadIdx.x;
  if (i < n) p[i] = 0;
}

__global__ void hist_kernel(const int* __restrict__ dst, int* __restrict__ cnt, int ne) {
  int e = blockIdx.x * 256 + threadIdx.x;
  if (e < ne) atomicAdd(&cnt[dst[e]], 1);
}

__global__ __launch_bounds__(1024) void scan_kernel(const int* __restrict__ cnt,
                                                    int* __restrict__ row_ptr,
                                                    int* __restrict__ row_next, int n) {
  __shared__ int part[1024];
  int t = threadIdx.x;
  int per = (n + 1023) / 1024;
  int base = t * per;
  int local = 0;
  for (int i = 0; i < per; ++i) {
    int idx = base + i;
    if (idx < n) local += cnt[idx];
  }
  part[t] = local;
  __syncthreads();
  for (int off = 1; off < 1024; off <<= 1) {
    int v = (t >= off) ? part[t - off] : 0;
    __syncthreads();
    part[t] += v;
    __syncthreads();
  }
  int prefix = (t == 0) ? 0 : part[t - 1];
  for (int i = 0; i < per; ++i) {
    int idx = base + i;
    if (idx < n) {
      row_ptr[idx] = prefix;
      row_next[idx] = prefix;
      prefix += cnt[idx];
    }
  }
  if (t == 1023) row_ptr[n] = part[1023];
}

__global__ void fill_kernel(const int* __restrict__ dst, int* __restrict__ row_next,
                            int* __restrict__ csr_eid, int ne) {
  int e = blockIdx.x * 256 + threadIdx.x;
  if (e >= ne) return;
  int pos = atomicAdd(&row_next[dst[e]], 1);
  csr_eid[pos] = e;
}

// ---------------- prep_all: in_proj (blocks 0..4999) + wt cast (5000..5383) + aeproj (5384) ---

__global__ void prep_all_kernel(const float* __restrict__ x, const float* __restrict__ Wp,
                                const float* __restrict__ bp, unsigned short* __restrict__ h_bf,
                                const float* __restrict__ W1, const float* __restrict__ W2,
                                const float* __restrict__ W3, unsigned short* __restrict__ Bt1,
                                unsigned short* __restrict__ Bt2, unsigned short* __restrict__ Bt3,
                                const float* __restrict__ We1, const float* __restrict__ ae1,
                                const float* __restrict__ We2, const float* __restrict__ ae2,
                                const float* __restrict__ We3, const float* __restrict__ ae3,
                                float* __restrict__ proj) {
  int b = blockIdx.x, t = threadIdx.x;
  if (b < 5000) {
    int i = b * 256 + t;
    int node = i >> 6, c = i & 63;
    float v = x[node * 2] * Wp[c] + x[node * 2 + 1] * Wp[64 + c] + bp[c];
    h_bf[i] = bf16_rne(elu_f(v));
  } else if (b < 5384) {
    int idx = (b - 5000) * 256 + t;
    const float* W; unsigned short* Bt; int K, Nc, local;
    if (idx < 16384)      { W = W1; Bt = Bt1; K = 64;  Nc = 256; local = idx; }
    else if (idx < 81920) { W = W2; Bt = Bt2; K = 256; Nc = 256; local = idx - 16384; }
    else if (idx < 98304) { W = W3; Bt = Bt3; K = 256; Nc = 64;  local = idx - 81920; }
    else return;
    int k = local / Nc, n = local - k * Nc;
    Bt[(size_t)n * K + k] = bf16_rne(W[local]);
  } else {
    if (t < 12) {
      int d = t >> 2, h = t & 3;
      float s = 0.f;
      for (int c = 0; c < 64; ++c) s += We1[d * 256 + h * 64 + c] * ae1[h * 64 + c];
      proj[t] = s;
    } else if (t < 24) {
      int u = t - 12; int d = u >> 2, h = u & 3;
      float s = 0.f;
      for (int c = 0; c < 64; ++c) s += We2[d * 256 + h * 64 + c] * ae2[h * 64 + c];
      proj[12 + u] = s;
    } else if (t < 27) {
      int d = t - 24;
      float s = 0.f;
      for (int c = 0; c < 64; ++c) s += We3[d * 64 + c] * ae3[c];
      proj[24 + d] = s;
    }
  }
}

// ---------------- edge prep: CSR-order src + per-layer edge-dot planes --------------

__global__ void edge_prep_kernel(const int* __restrict__ csr_eid, const int* __restrict__ src,
                                 const float* __restrict__ ea, const float* __restrict__ proj,
                                 int* __restrict__ csr_src, float* __restrict__ edot) {
  int i = blockIdx.x * 256 + threadIdx.x;
  if (i >= N_EDGES) return;
  int eid = csr_eid[i];
  csr_src[i] = src[eid];
  float e0 = ea[eid * 3 + 0], e1 = ea[eid * 3 + 1], e2 = ea[eid * 3 + 2];
  #pragma unroll
  for (int h = 0; h < 4; ++h)
    edot[(size_t)h * N_EDGES + i] = e0 * proj[h] + e1 * proj[4 + h] + e2 * proj[8 + h];
  #pragma unroll
  for (int h = 0; h < 4; ++h)
    edot[(size_t)(4 + h) * N_EDGES + i] = e0 * proj[12 + h] + e1 * proj[16 + h] + e2 * proj[20 + h];
  edot[(size_t)8 * N_EDGES + i] = e0 * proj[24] + e1 * proj[25] + e2 * proj[26];
}

// ---------------- MFMA bf16 GEMM + fused alpha epilogue ----------------------------

template <int KDIM>
__global__ __launch_bounds__(256) void mfma_gemm_alpha_kernel(
    const unsigned short* __restrict__ A, const unsigned short* __restrict__ Bt,
    unsigned short* __restrict__ C_bf, const float* __restrict__ a_src,
    const float* __restrict__ a_dst, float* __restrict__ alp_s,
    float* __restrict__ alp_d, int M, int Nc) {
  __shared__ unsigned short As[64][40];
  __shared__ unsigned short Bs[64][40];
  int t = threadIdx.x;
  int wave = t >> 6, lane = t & 63;
  int m_frag = lane & 15, quad = lane >> 4;
  int row0 = blockIdx.y * 64, col0 = blockIdx.x * 64;
  int lr = t >> 2;
  int lk = (t & 3) * 8;
  floatx4 acc[4];
  #pragma unroll
  for (int c = 0; c < 4; ++c) acc[c] = (floatx4){0.f, 0.f, 0.f, 0.f};

  for (int k0 = 0; k0 < KDIM; k0 += 32) {
    int gr = row0 + lr;
    short8 av = {0, 0, 0, 0, 0, 0, 0, 0};
    if (gr < M) av = *(const short8*)(A + (size_t)gr * KDIM + k0 + lk);
    *(short8*)(&As[lr][lk]) = av;
    short8 bv = *(const short8*)(Bt + (size_t)(col0 + lr) * KDIM + k0 + lk);
    *(short8*)(&Bs[lr][lk]) = bv;
    __syncthreads();
    short8 a = *(const short8*)(&As[wave * 16 + m_frag][quad * 8]);
    #pragma unroll
    for (int c = 0; c < 4; ++c) {
      short8 b = *(const short8*)(&Bs[c * 16 + m_frag][quad * 8]);
      acc[c] = __builtin_amdgcn_mfma_f32_16x16x32_bf16(a, b, acc[c], 0, 0, 0);
    }
    __syncthreads();
  }

  int H = Nc >> 6;
  int head = blockIdx.x;
  float ps[4] = {}, pd[4] = {};
  #pragma unroll
  for (int c = 0; c < 4; ++c) {
    float asv = a_src[head * 64 + c * 16 + m_frag];
    float adv = a_dst[head * 64 + c * 16 + m_frag];
    #pragma unroll
    for (int i = 0; i < 4; ++i) {
      ps[i] += acc[c][i] * asv;
      pd[i] += acc[c][i] * adv;
    }
  }
  #pragma unroll
  for (int off = 1; off < 16; off <<= 1) {
    #pragma unroll
    for (int i = 0; i < 4; ++i) {
      ps[i] += __shfl_xor(ps[i], off);
      pd[i] += __shfl_xor(pd[i], off);
    }
  }
  #pragma unroll
  for (int c = 0; c < 4; ++c) {
    #pragma unroll
    for (int i = 0; i < 4; ++i) {
      int gr = row0 + wave * 16 + quad * 4 + i;
      if (gr < M) C_bf[(size_t)gr * Nc + col0 + c * 16 + m_frag] = bf16_rne(acc[c][i]);
    }
  }
  if (m_frag == 0) {
    #pragma unroll
    for (int i = 0; i < 4; ++i) {
      int gr = row0 + wave * 16 + quad * 4 + i;
      if (gr < M) {
        alp_s[gr * H + head] = ps[i];
        alp_d[gr * H + head] = pd[i];
      }
    }
  }
}

// ---------------- fused softmax + aggregate, H=4 (block per node) -------------------

template <bool OUT_BF>
__global__ __launch_bounds__(256) void softagg4_kernel(
    const int* __restrict__ row_ptr, const int* __restrict__ csr_src,
    const float* __restrict__ edot, const float* __restrict__ alp_s,
    const float* __restrict__ alp_d, const unsigned short* __restrict__ xh_bf,
    const float* __restrict__ bias, float* __restrict__ out,
    unsigned short* __restrict__ out_bf) {
  constexpr int HC = 256, H = 4, CHUNK = 256, L = 32, S = 8;
  __shared__ float lds_w[H][CHUNK + 8];   // +8: heads hit distinct banks in phase 2
  __shared__ int lds_src[CHUNK];
  __shared__ float sh_r[H];
  __shared__ float sh_inv[H];
  __shared__ float red[4 * HC];

  int n = blockIdx.x;
  int t = threadIdx.x;
  int wave = t >> 6, lane = t & 63;
  int slot = t / L, l = t % L;
  int head2 = (8 * l) >> 6;
  int s0 = row_ptr[n], s1 = row_ptr[n + 1];

  float m_run = -INFINITY, s_run = 0.f;
  float2v accp[4] = {};
  float adv = alp_d[n * H + wave];
  const float* __restrict__ edot_h = edot + (size_t)wave * N_EDGES;

  for (int c0 = s0; c0 < s1; c0 += CHUNK) {
    int cend = min(s1, c0 + CHUNK);
    {
      int h = wave;
      float cm = -INFINITY;
      for (int i = c0 + lane; i < cend; i += 64) {
        int s = csr_src[i];
        if (h == 0) lds_src[i - c0] = s;
        float a = alp_s[s * H + h] + adv + edot_h[i];
        a = a > 0.f ? a : 0.2f * a;
        lds_w[h][i - c0] = a;
        cm = fmaxf(cm, a);
      }
      #pragma unroll
      for (int off = 1; off < 64; off <<= 1) cm = fmaxf(cm, __shfl_xor(cm, off));
      float m_new = fmaxf(m_run, cm);
      float r = __expf(m_run - m_new);
      float se = 0.f;
      for (int i = c0 + lane; i < cend; i += 64) {
        float w = __expf(lds_w[h][i - c0] - m_new);
        lds_w[h][i - c0] = w;
        se += w;
      }
      #pragma unroll
      for (int off = 1; off < 64; off <<= 1) se += __shfl_xor(se, off);
      s_run = s_run * r + se;
      m_run = m_new;
      if (lane == 0) sh_r[h] = r;
    }
    __syncthreads();
    float2v rrp = {sh_r[head2], sh_r[head2]};
    #pragma unroll
    for (int d = 0; d < 4; ++d) accp[d] *= rrp;
    int i = c0 + slot;
    for (; i + S < cend; i += 2 * S) {
      int sA = lds_src[i - c0];
      int sB = lds_src[i - c0 + S];
      float wA = lds_w[head2][i - c0];
      float wB = lds_w[head2][i - c0 + S];
      uint4 uA = *(const uint4*)(xh_bf + (size_t)sA * HC + l * 8);
      uint4 uB = *(const uint4*)(xh_bf + (size_t)sB * HC + l * 8);
      float2v wAp = {wA, wA}, wBp = {wB, wB};
      accp[0] = __builtin_elementwise_fma(unpack_bf2(uA.x), wAp, accp[0]);
      accp[1] = __builtin_elementwise_fma(unpack_bf2(uA.y), wAp, accp[1]);
      accp[2] = __builtin_elementwise_fma(unpack_bf2(uA.z), wAp, accp[2]);
      accp[3] = __builtin_elementwise_fma(unpack_bf2(uA.w), wAp, accp[3]);
      accp[0] = __builtin_elementwise_fma(unpack_bf2(uB.x), wBp, accp[0]);
      accp[1] = __builtin_elementwise_fma(unpack_bf2(uB.y), wBp, accp[1]);
      accp[2] = __builtin_elementwise_fma(unpack_bf2(uB.z), wBp, accp[2]);
      accp[3] = __builtin_elementwise_fma(unpack_bf2(uB.w), wBp, accp[3]);
    }
    if (i < cend) {
      int s = lds_src[i - c0];
      float w = lds_w[head2][i - c0];
      uint4 u = *(const uint4*)(xh_bf + (size_t)s * HC + l * 8);
      float2v wp = {w, w};
      accp[0] = __builtin_elementwise_fma(unpack_bf2(u.x), wp, accp[0]);
      accp[1] = __builtin_elementwise_fma(unpack_bf2(u.y), wp, accp[1]);
      accp[2] = __builtin_elementwise_fma(unpack_bf2(u.z), wp, accp[2]);
      accp[3] = __builtin_elementwise_fma(unpack_bf2(u.w), wp, accp[3]);
    }
    __syncthreads();
  }
  if (lane == 0) sh_inv[wave] = 1.0f / (s_run + 1e-16f);
  __syncthreads();
  float2v invp = {sh_inv[head2], sh_inv[head2]};
  #pragma unroll
  for (int d = 0; d < 4; ++d) accp[d] *= invp;
  float accf[8];
  #pragma unroll
  for (int d = 0; d < 4; ++d) { accf[2 * d] = accp[d].x; accf[2 * d + 1] = accp[d].y; }
  #pragma unroll
  for (int off = L; off < 64; off <<= 1) {
    #pragma unroll
    for (int j = 0; j < 8; ++j) accf[j] += __shfl_xor(accf[j], off);
  }
  if (lane < L) {
    #pragma unroll
    for (int j = 0; j < 8; ++j) red[wave * HC + swz(lane * 8 + j)] = accf[j];
  }
  __syncthreads();
  {
    int pos = swz(t & (HC - 1));
    float a = red[0 * HC + pos] + red[1 * HC + pos] + red[2 * HC + pos] + red[3 * HC + pos];
    a += bias[t];
    a = elu_f(a);
    if (OUT_BF) out_bf[(size_t)n * HC + t] = bf16_rne(a);
    else out[(size_t)n * HC + t] = a;
  }
}

// ---------------- layer-3 softagg (wave per node, H=1, HC=64) + fused classifier ----

__global__ __launch_bounds__(256) void softagg_cls_kernel(
    const int* __restrict__ row_ptr, const int* __restrict__ csr_src,
    const float* __restrict__ edot, const float* __restrict__ alp_s,
    const float* __restrict__ alp_d, const unsigned short* __restrict__ xh_bf,
    const float* __restrict__ b3, const float* __restrict__ Wc,
    const float* __restrict__ bc, float* __restrict__ out, int n_nodes) {
  constexpr int CHUNK = 256;
  __shared__ float lds_w[4][CHUNK];
  __shared__ int lds_s[4][CHUNK];

  int wave = threadIdx.x >> 6, lane = threadIdx.x & 63;
  int n = blockIdx.x * 4 + wave;
  if (n >= n_nodes) return;
  int slot = lane >> 3, l = lane & 7;
  int s0 = row_ptr[n], s1 = row_ptr[n + 1];

  float m_run = -INFINITY, s_run = 0.f;
  float2v accp[4] = {};
  float adv = alp_d[n];

  for (int c0 = s0; c0 < s1; c0 += CHUNK) {
    int cend = min(s1, c0 + CHUNK);
    float cm = -INFINITY;
    for (int i = c0 + lane; i < cend; i += 64) {
      int s = csr_src[i];
      lds_s[wave][i - c0] = s;
      float a = alp_s[s] + adv + edot[i];
      a = a > 0.f ? a : 0.2f * a;
      lds_w[wave][i - c0] = a;
      cm = fmaxf(cm, a);
    }
    #pragma unroll
    for (int off = 1; off < 64; off <<= 1) cm = fmaxf(cm, __shfl_xor(cm, off));
    float m_new = fmaxf(m_run, cm);
    float r = __expf(m_run - m_new);
    float se = 0.f;
    for (int i = c0 + lane; i < cend; i += 64) {
      float w = __expf(lds_w[wave][i - c0] - m_new);
      lds_w[wave][i - c0] = w;
      se += w;
    }
    #pragma unroll
    for (int off = 1; off < 64; off <<= 1) se += __shfl_xor(se, off);
    s_run = s_run * r + se;
    m_run = m_new;
    float2v rp = {r, r};
    #pragma unroll
    for (int d = 0; d < 4; ++d) accp[d] *= rp;
    for (int i = c0 + slot; i < cend; i += 8) {
      int s = lds_s[wave][i - c0];
      float w = lds_w[wave][i - c0];
      uint4 u = *(const uint4*)(xh_bf + (size_t)s * 64 + l * 8);
      float2v wp = {w, w};
      accp[0] = __builtin_elementwise_fma(unpack_bf2(u.x), wp, accp[0]);
      accp[1] = __builtin_elementwise_fma(unpack_bf2(u.y), wp, accp[1]);
      accp[2] = __builtin_elementwise_fma(unpack_bf2(u.z), wp, accp[2]);
      accp[3] = __builtin_elementwise_fma(unpack_bf2(u.w), wp, accp[3]);
    }
  }
  float inv = 1.0f / (s_run + 1e-16f);
  float2v invp = {inv, inv};
  #pragma unroll
  for (int d = 0; d < 4; ++d) accp[d] *= invp;
  float accf[8];
  #pragma unroll
  for (int d = 0; d < 4; ++d) { accf[2 * d] = accp[d].x; accf[2 * d + 1] = accp[d].y; }
  // reduce the 8 slots (lanes strided by 8)
  #pragma unroll
  for (int off = 8; off < 64; off <<= 1) {
    #pragma unroll
    for (int j = 0; j < 8; ++j) accf[j] += __shfl_xor(accf[j], off);
  }
  // classifier: each lane handles its 8 channels (c = l*8+j), partial dots
  float p0 = 0.f, p1 = 0.f, p2 = 0.f, p3 = 0.f;
  #pragma unroll
  for (int j = 0; j < 8; ++j) {
    int c = l * 8 + j;
    float v = accf[j] + b3[c];
    p0 += v * Wc[c * 4 + 0];
    p1 += v * Wc[c * 4 + 1];
    p2 += v * Wc[c * 4 + 2];
    p3 += v * Wc[c * 4 + 3];
  }
  #pragma unroll
  for (int off = 1; off < 8; off <<= 1) {
    p0 += __shfl_xor(p0, off);
    p1 += __shfl_xor(p1, off);
    p2 += __shfl_xor(p2, off);
    p3 += __shfl_xor(p3, off);
  }
  if (lane == 0) {
    p0 += bc[0]; p1 += bc[1]; p2 += bc[2]; p3 += bc[3];
    float mx = fmaxf(fmaxf(p0, p1), fmaxf(p2, p3));
    float e0 = __expf(p0 - mx), e1 = __expf(p1 - mx), e2 = __expf(p2 - mx), e3 = __expf(p3 - mx);
    float s = 1.f / (e0 + e1 + e2 + e3);
    out[n * 4 + 0] = e0 * s;
    out[n * 4 + 1] = e1 * s;
    out[n * 4 + 2] = e2 * s;
    out[n * 4 + 3] = e3 * s;
  }
}

// ---------------- host ----------------

extern "C" void kernel_launch(void* const* d_in, const int* in_sizes, int n_in,
                              void* d_out, int out_size, void* d_ws, size_t ws_size,
                              hipStream_t stream) {
  const float* x   = (const float*)d_in[0];
  const int*   ei  = (const int*)d_in[1];
  const float* ea  = (const float*)d_in[2];
  const float* Wp  = (const float*)d_in[3];
  const float* bp  = (const float*)d_in[4];
  const float* W1  = (const float*)d_in[5];
  const float* We1 = (const float*)d_in[6];
  const float* as1 = (const float*)d_in[7];
  const float* ad1 = (const float*)d_in[8];
  const float* ae1 = (const float*)d_in[9];
  const float* b1  = (const float*)d_in[10];
  const float* W2  = (const float*)d_in[11];
  const float* We2 = (const float*)d_in[12];
  const float* as2 = (const float*)d_in[13];
  const float* ad2 = (const float*)d_in[14];
  const float* ae2 = (const float*)d_in[15];
  const float* b2  = (const float*)d_in[16];
  const float* W3  = (const float*)d_in[17];
  const float* We3 = (const float*)d_in[18];
  const float* as3 = (const float*)d_in[19];
  const float* ad3 = (const float*)d_in[20];
  const float* ae3 = (const float*)d_in[21];
  const float* b3  = (const float*)d_in[22];
  const float* Wc  = (const float*)d_in[23];
  const float* bc  = (const float*)d_in[24];
  float* out = (float*)d_out;

  const int* src = ei;
  const int* dst = ei + N_EDGES;

  char* wptr = (char*)d_ws;
  auto alloc = [&](size_t bytes) {
    char* p = wptr;
    wptr += (bytes + 255) & ~(size_t)255;
    return p;
  };
  int*            cnt      = (int*)alloc((size_t)N_NODES * 4);
  int*            row_ptr  = (int*)alloc((size_t)(N_NODES + 1) * 4);
  int*            row_next = (int*)alloc((size_t)N_NODES * 4);
  int*            csr_eid  = (int*)alloc((size_t)N_EDGES * 4);
  int*            csr_src  = (int*)alloc((size_t)N_EDGES * 4);
  float*          edot     = (float*)alloc((size_t)9 * N_EDGES * 4);
  unsigned short* hA_bf    = (unsigned short*)alloc((size_t)N_NODES * 256 * 2);
  unsigned short* hX_bf    = (unsigned short*)alloc((size_t)N_NODES * 256 * 2);
  float*          alp_s    = (float*)alloc((size_t)N_NODES * 4 * 4);
  float*          alp_d    = (float*)alloc((size_t)N_NODES * 4 * 4);
  float*          proj     = (float*)alloc(32 * 4);
  unsigned short* Bt1      = (unsigned short*)alloc((size_t)64 * 256 * 2);
  unsigned short* Bt2      = (unsigned short*)alloc((size_t)256 * 256 * 2);
  unsigned short* Bt3      = (unsigned short*)alloc((size_t)256 * 64 * 2);

  // ---- CSR build ----
  zero_int_kernel<<<(N_NODES + 255) / 256, 256, 0, stream>>>(cnt, N_NODES);
  hist_kernel<<<(N_EDGES + 255) / 256, 256, 0, stream>>>(dst, cnt, N_EDGES);
  scan_kernel<<<1, 1024, 0, stream>>>(cnt, row_ptr, row_next, N_NODES);
  fill_kernel<<<(N_EDGES + 255) / 256, 256, 0, stream>>>(dst, row_next, csr_eid, N_EDGES);

  // ---- prep (in_proj + weight cast + aeproj in one) ----
  prep_all_kernel<<<5385, 256, 0, stream>>>(x, Wp, bp, hA_bf, W1, W2, W3, Bt1, Bt2, Bt3,
                                            We1, ae1, We2, ae2, We3, ae3, proj);
  edge_prep_kernel<<<(N_EDGES + 255) / 256, 256, 0, stream>>>(csr_eid, src, ea, proj,
                                                              csr_src, edot);

  dim3 g256(4, (N_NODES + 63) / 64);
  dim3 g64(1, (N_NODES + 63) / 64);

  // ---- layer 1: 64 -> 4x64, ELU ----
  mfma_gemm_alpha_kernel<64><<<g256, 256, 0, stream>>>(hA_bf, Bt1, hX_bf, as1, ad1,
                                                       alp_s, alp_d, N_NODES, 256);
  softagg4_kernel<true><<<N_NODES, 256, 0, stream>>>(row_ptr, csr_src,
                                                     edot + (size_t)0 * N_EDGES,
                                                     alp_s, alp_d, hX_bf, b1, nullptr, hA_bf);

  // ---- layer 2: 256 -> 4x64, ELU ----
  mfma_gemm_alpha_kernel<256><<<g256, 256, 0, stream>>>(hA_bf, Bt2, hX_bf, as2, ad2,
                                                        alp_s, alp_d, N_NODES, 256);
  softagg4_kernel<true><<<N_NODES, 256, 0, stream>>>(row_ptr, csr_src,
                                                     edot + (size_t)4 * N_EDGES,
                                                     alp_s, alp_d, hX_bf, b2, nullptr, hA_bf);

  // ---- layer 3: 256 -> 1x64 + classifier + softmax ----
  mfma_gemm_alpha_kernel<256><<<g64, 256, 0, stream>>>(hA_bf, Bt3, hX_bf, as3, ad3,
                                                       alp_s, alp_d, N_NODES, 64);
  softagg_cls_kernel<<<(N_NODES + 3) / 4, 256, 0, stream>>>(row_ptr, csr_src,
                                                            edot + (size_t)8 * N_EDGES,
                                                            alp_s, alp_d, hX_bf, b3, Wc, bc,
                                                            out, N_NODES);
}